// Round 10
// baseline (200.599 us; speedup 1.0000x reference)
//
#include <hip/hip_runtime.h>
#include <hip/hip_bf16.h>

#define N_NODES 50000
#define N_EDGES 800000
#define D 128

#define SB     3125      // bucket = dst>>4 (16 nodes); 50000 = 3125*16 exactly
#define SBP    3200      // padded bucket count (scan/counter arrays)
#define WCAP16 384       // window slots/bucket; lambda=256, +8 sigma
#define EPB    8192      // edges per scatter block
#define SBLK   98        // ceil(800000/8192)
#define CONV_BLOCKS 3200
#define SHARD_STRIDE 1600000   // 50000*32 ushorts = 3.2 MB per column shard

using bf16x8 = __attribute__((ext_vector_type(8))) short;   // 8 bf16 (4 VGPRs)
using u16x8  = __attribute__((ext_vector_type(8))) unsigned short;
using f32x4  = __attribute__((ext_vector_type(4))) float;   // MFMA C/D

static __device__ __forceinline__ ushort f2bf(float f) {
    __hip_bfloat16 h = __float2bfloat16(f);   // RNE
    return *reinterpret_cast<ushort*>(&h);
}
static __device__ __forceinline__ float bf2f(ushort u) {
    return __uint_as_float(((unsigned)u) << 16);
}

// ---------------------------------------------------------------------------
// ws layout (~33.2 MB): bcnt[SBP*16] int (200 KB, 64B-padded counters),
// pairs[SB*WCAP16] u32 (4.8 MB), snode[SB*WCAP16] ushort (2.4 MB, node-
// sorted src), od[SB*16] int (200 KB, beg|deg<<16), xb (12.8 MB),
// aggS[4][50000][32] bf16 (12.8 MB, SHARD-MAJOR).
// r9 lesson: gather stuck at ~50us across depth/locality variants = random
// 256B row pulls at ~4 TB/s fabric. This round: COLUMN-SHARDED gather —
// 4 shards x 32 cols (64B slices); shard slice = 3.2 MB fits ONE XCD L2;
// blockIdx = b*4+s -> round-robin puts shard s on XCDs {s,s+4} only.
// ---------------------------------------------------------------------------

// Streaming: x -> bf16 + zero bcnt (no memset dispatch).
__global__ void __launch_bounds__(256)
convert_x(const float4* __restrict__ x4, ushort* __restrict__ xb,
          int* __restrict__ bcnt) {
    const int gt = blockIdx.x * 256 + threadIdx.x;
    if (gt < SBP * 16) bcnt[gt] = 0;
    const int total4 = N_NODES * D / 4;    // 1.6M
    const int stride = CONV_BLOCKS * 256;  // 819200
    for (int j = gt; j < total4; j += stride) {
        float4 v = x4[j];
        ushort4 u = make_ushort4(f2bf(v.x), f2bf(v.y), f2bf(v.z), f2bf(v.w));
        *(ushort4*)(xb + (size_t)j * 4) = u;
    }
}

// Counting-sort scatter to 16-node buckets (r8-verified): LDS histogram ->
// Hillis-Steele scan over 3200 -> LDS place -> coalesced run writes.
__global__ void __launch_bounds__(1024)
scatter_radix(const int* __restrict__ src, const int* __restrict__ dst,
              int* __restrict__ bcnt, unsigned* __restrict__ pairs) {
    __shared__ int      A[SBP];            // scan -> delta      (12.8 KB)
    __shared__ int      B[SBP];            // cnt -> lcur        (12.8 KB)
    __shared__ unsigned payload[EPB];      // sorted edges       (32 KB)
    const int tid = threadIdx.x;
    const int base = blockIdx.x * EPB;
    int nblk = N_EDGES - base;
    if (nblk > EPB) nblk = EPB;

    for (int i = tid; i < SBP; i += 1024) A[i] = 0;
    __syncthreads();

    unsigned pk[8];
#pragma unroll
    for (int k = 0; k < 8; ++k) {
        int i = k * 1024 + tid;
        pk[k] = 0xFFFFFFFFu;               // sentinel
        if (i < nblk) {
            int e = base + i;
            pk[k] = (unsigned)src[e] | ((unsigned)dst[e] << 16);
            atomicAdd(&A[pk[k] >> 20], 1);     // bucket = dst>>4
        }
    }
    __syncthreads();

    for (int i = tid; i < SBP; i += 1024) B[i] = A[i];   // save counts
    __syncthreads();

    for (int off = 1; off < SBP; off <<= 1) {   // inclusive scan, 12 steps
        int t[4];
#pragma unroll
        for (int k = 0; k < 4; ++k) {
            int i = tid + k * 1024;
            t[k] = (i < SBP && i >= off) ? A[i - off] : 0;
        }
        __syncthreads();
#pragma unroll
        for (int k = 0; k < 4; ++k) {
            int i = tid + k * 1024;
            if (i < SBP) A[i] += t[k];
        }
        __syncthreads();
    }

    for (int i = tid; i < SBP; i += 1024) {
        int incl = A[i], cnt = B[i];
        int excl = incl - cnt;
        int gb = cnt ? atomicAdd(&bcnt[i * 16], cnt) : 0;  // padded counter
        A[i] = i * WCAP16 + gb - excl;     // delta
        B[i] = excl;                       // lcur
    }
    __syncthreads();

#pragma unroll
    for (int k = 0; k < 8; ++k) {          // place into LDS (bucket-sorted)
        unsigned p = pk[k];
        if (p != 0xFFFFFFFFu) {
            int pos = atomicAdd(&B[p >> 20], 1);
            payload[pos] = p;
        }
    }
    __syncthreads();

#pragma unroll
    for (int k = 0; k < 8; ++k) {          // coalesced run writes
        int i = k * 1024 + tid;
        if (i < nblk) {
            unsigned p = payload[i];
            int bkt = (int)(p >> 20);
            int addr = i + A[bkt];
            if (addr < (bkt + 1) * WCAP16)     // 8-sigma guard, never trips
                pairs[addr] = p;
        }
    }
}

// Per-bucket node sort (done ONCE, so the x4-replicated sharded gather has
// zero CSR work): window -> regs -> 16-key histogram -> scan -> place ->
// node-sorted src (ushort) + packed offsets beg|deg<<16.
__global__ void __launch_bounds__(256)
node_sort(const unsigned* __restrict__ pairs, const int* __restrict__ bcnt,
          ushort* __restrict__ snode, int* __restrict__ od) {
    __shared__ ushort buf[WCAP16];
    __shared__ int h16[16], cur16[16];
    const int b = blockIdx.x, tid = threadIdx.x;
    int cnt = bcnt[b * 16];
    if (cnt > WCAP16) cnt = WCAP16;
    unsigned p0 = 0xFFFFFFFFu, p1 = 0xFFFFFFFFu;
    if (tid < cnt)       p0 = pairs[b * WCAP16 + tid];
    if (tid + 256 < cnt) p1 = pairs[b * WCAP16 + 256 + tid];
    if (tid < 16) h16[tid] = 0;
    __syncthreads();
    if (p0 != 0xFFFFFFFFu) atomicAdd(&h16[(p0 >> 16) & 15], 1);
    if (p1 != 0xFFFFFFFFu) atomicAdd(&h16[(p1 >> 16) & 15], 1);
    __syncthreads();
    if (tid < 16) {                        // 16-lane inclusive shfl scan
        int v = h16[tid], incl = v;
#pragma unroll
        for (int o = 1; o < 16; o <<= 1) {
            int t = __shfl_up(incl, o, 64);
            if (tid >= o) incl += t;
        }
        int excl = incl - v;
        cur16[tid] = excl;
        od[b * 16 + tid] = excl | (v << 16);
    }
    __syncthreads();
    if (p0 != 0xFFFFFFFFu) { int pos = atomicAdd(&cur16[(p0 >> 16) & 15], 1); buf[pos] = (ushort)(p0 & 0xFFFFu); }
    if (p1 != 0xFFFFFFFFu) { int pos = atomicAdd(&cur16[(p1 >> 16) & 15], 1); buf[pos] = (ushort)(p1 & 0xFFFFu); }
    __syncthreads();
    if (tid < cnt)       snode[b * WCAP16 + tid]       = buf[tid];
    if (tid + 256 < cnt) snode[b * WCAP16 + 256 + tid] = buf[tid + 256];
}

// ---------------------------------------------------------------------------
// Column-sharded gather: block = (bucket b, shard s), blockIdx = b*4+s so
// round-robin XCD assignment pins shard s to XCDs {s,s+4} -> each XCD reads
// only its 3.2 MB xb slice (L2-resident). Per node: 16 edges x 64B in
// flight (4 lanes x 16B per edge), shfl reduce, shard-major contiguous
// write. No CSR work (windows pre-sorted by node_sort).
// ---------------------------------------------------------------------------
__global__ void __launch_bounds__(256)
gather_shard(const ushort* __restrict__ snode, const int* __restrict__ od,
             const ushort* __restrict__ xb, ushort* __restrict__ aggS) {
    __shared__ ushort lsw[WCAP16];
    __shared__ int od16[16];
    const int tid = threadIdx.x;
    const int b = blockIdx.x >> 2;
    const int s = blockIdx.x & 3;
    if (tid < WCAP16 / 4)                  // 96 x ushort4 = 768 B
        ((ushort4*)lsw)[tid] = ((const ushort4*)(snode + (size_t)b * WCAP16))[tid];
    if (tid < 16) od16[tid] = od[b * 16 + tid];
    __syncthreads();

    const int wv = tid >> 6, lane = tid & 63;
    const int es = lane >> 2, sub = lane & 3;       // 16 edge slots x 4 lanes
    const ushort* xs = xb + s * 32 + sub * 8;       // this lane's 16B of 64B slice

#pragma unroll 1
    for (int k = wv * 4; k < wv * 4 + 4; ++k) {
        const int o = od16[k];
        const int beg = o & 0xFFFF, deg = o >> 16;
        float acc[8];
#pragma unroll
        for (int j = 0; j < 8; ++j) acc[j] = 0.f;

        const int steps = (deg + 15) >> 4;
#pragma unroll 1
        for (int t = 0; t < steps; ++t) {
            int slot = t * 16 + es;
            int idx = beg + ((slot < deg) ? slot : 0);   // slot-0 reload trick
            int sn = lsw[idx];
            u16x8 u = *(const u16x8*)(xs + (size_t)sn * D);
            if (slot < deg) {
#pragma unroll
                for (int j = 0; j < 8; ++j) acc[j] += bf2f(u[j]);
            }
        }
#pragma unroll
        for (int j = 0; j < 8; ++j) {      // sum the 16 edge slots
            acc[j] += __shfl_xor(acc[j], 4, 64);
            acc[j] += __shfl_xor(acc[j], 8, 64);
            acc[j] += __shfl_xor(acc[j], 16, 64);
            acc[j] += __shfl_xor(acc[j], 32, 64);
        }
        if (lane < 4) {                    // lanes 0..3 hold sub-chunks 0..3
            u16x8 u;
#pragma unroll
            for (int j = 0; j < 8; ++j) u[j] = f2bf(acc[j]);
            *(u16x8*)(aggS + (size_t)s * SHARD_STRIDE
                      + (size_t)(b * 16 + k) * 32 + lane * 8) = u;
        }
    }
}

// ---------------------------------------------------------------------------
// MFMA GEMM (r8-verified body): out[n][o] = relu(sum_k agg[n][k]*W[o][k]) +
// x[n][o]. A-fragments from SHARD-MAJOR aggS: col = kb*32+q*8 lies wholly
// in shard kb, so shard index == kb. W staged fp32->bf16 in LDS.
// ---------------------------------------------------------------------------
__global__ void __launch_bounds__(256)
gemm_relu_res(const ushort* __restrict__ aggS,
              const float* __restrict__ W,
              const ushort* __restrict__ xb,
              float* __restrict__ out) {
    __shared__ __align__(16) char lds[33792];
    ushort* Wl = (ushort*)lds;                   // chunk-major [k/8][o][8]

    const int tid  = threadIdx.x;
    const int lane = tid & 63;
    const int wv   = tid >> 6;
    const int m16  = lane & 15;
    const int q    = lane >> 4;

#pragma unroll
    for (int i = 0; i < 8; ++i) {
        int g  = tid + i * 256;
        int o  = g & 127;
        int kc = g >> 7;
        const float4* wp = (const float4*)(W + (size_t)o * D + kc * 8);
        float4 w0 = wp[0], w1 = wp[1];
        bf16x8 hv;
        hv[0] = (short)f2bf(w0.x); hv[1] = (short)f2bf(w0.y);
        hv[2] = (short)f2bf(w0.z); hv[3] = (short)f2bf(w0.w);
        hv[4] = (short)f2bf(w1.x); hv[5] = (short)f2bf(w1.y);
        hv[6] = (short)f2bf(w1.z); hv[7] = (short)f2bf(w1.w);
        *(bf16x8*)&Wl[g * 8] = hv;
    }
    __syncthreads();

    const int nb = blockIdx.x * 64 + wv * 16;
    int arow = nb + m16;
    if (arow >= N_NODES) arow = N_NODES - 1;     // clamp: rows >= N never stored

    bf16x8 a[4];
#pragma unroll
    for (int kb = 0; kb < 4; ++kb)               // shard == kb
        a[kb] = *(const bf16x8*)&aggS[(size_t)kb * SHARD_STRIDE
                                      + (size_t)arow * 32 + q * 8];

    f32x4 acc[8];
#pragma unroll
    for (int t = 0; t < 8; ++t) {
        acc[t] = (f32x4){0.f, 0.f, 0.f, 0.f};
#pragma unroll
        for (int kb = 0; kb < 4; ++kb) {
            bf16x8 bfr = *(const bf16x8*)&Wl[(((kb * 4 + q) * 128) + t * 16 + m16) * 8];
            acc[t] = __builtin_amdgcn_mfma_f32_16x16x32_bf16(a[kb], bfr, acc[t], 0, 0, 0);
        }
    }

    __syncthreads();                              // Wl dead after this
    float* Ew = (float*)(lds + wv * 8448);        // 16 rows x 132 floats
#pragma unroll
    for (int t = 0; t < 8; ++t)
#pragma unroll
        for (int r = 0; r < 4; ++r)
            Ew[(q * 4 + r) * 132 + t * 16 + m16] = acc[t][r];

    const int h  = lane >> 5;
    const int c4 = (lane & 31) << 2;
#pragma unroll
    for (int j = 0; j < 8; ++j) {
        int r = j * 2 + h;
        int node = nb + r;
        if (node < N_NODES) {
            float4 v  = *(const float4*)&Ew[r * 132 + c4];
            ushort4 xu = *(const ushort4*)(xb + (size_t)node * D + c4);
            float4 o;
            o.x = fmaxf(v.x, 0.f) + bf2f(xu.x);
            o.y = fmaxf(v.y, 0.f) + bf2f(xu.y);
            o.z = fmaxf(v.z, 0.f) + bf2f(xu.z);
            o.w = fmaxf(v.w, 0.f) + bf2f(xu.w);
            *(float4*)(out + (size_t)node * D + c4) = o;
        }
    }
}

// ===================== minimal fallback (tiny ws; never expected) ==========
__global__ void zero_out(float4* __restrict__ p, int n4) {
    int i = blockIdx.x * 256 + threadIdx.x;
    if (i < n4) p[i] = make_float4(0.f, 0.f, 0.f, 0.f);
}
__global__ void scatter_edges(const float* __restrict__ x,
                              const int* __restrict__ src,
                              const int* __restrict__ dst,
                              float* __restrict__ agg) {
    long long tid = (long long)blockIdx.x * 256 + threadIdx.x;
    if (tid >= (long long)N_EDGES * 32) return;
    int edge = (int)(tid >> 5);
    int c    = ((int)tid & 31) << 2;
    const float4 v = *(const float4*)(x + (size_t)src[edge] * D + c);
    float* p = agg + (size_t)dst[edge] * D + c;
    unsafeAtomicAdd(p + 0, v.x);
    unsafeAtomicAdd(p + 1, v.y);
    unsafeAtomicAdd(p + 2, v.z);
    unsafeAtomicAdd(p + 3, v.w);
}
__global__ void __launch_bounds__(256)
gemm_relu_res_f32(float* data, const float* __restrict__ W,
                  const float* __restrict__ x) {
    __shared__ __align__(16) char lds[50176];
    ushort* Wl = (ushort*)lds;
    ushort* Al = (ushort*)(lds + 32768);
    const int tid  = threadIdx.x;
    const int lane = tid & 63;
    const int wv   = tid >> 6;
    const int m16  = lane & 15;
    const int q    = lane >> 4;
#pragma unroll
    for (int i = 0; i < 8; ++i) {
        int g  = tid + i * 256;
        int o  = g & 127;
        int kc = g >> 7;
        const float4* wp = (const float4*)(W + (size_t)o * D + kc * 8);
        float4 w0 = wp[0], w1 = wp[1];
        bf16x8 hv;
        hv[0] = (short)f2bf(w0.x); hv[1] = (short)f2bf(w0.y);
        hv[2] = (short)f2bf(w0.z); hv[3] = (short)f2bf(w0.w);
        hv[4] = (short)f2bf(w1.x); hv[5] = (short)f2bf(w1.y);
        hv[6] = (short)f2bf(w1.z); hv[7] = (short)f2bf(w1.w);
        *(bf16x8*)&Wl[g * 8] = hv;
    }
    __syncthreads();
    const int nb = blockIdx.x * 64 + wv * 16;
    ushort* Aw = &Al[wv * (16 * 136)];
#pragma unroll
    for (int m = 0; m < 16; ++m) {
        int node = nb + m;
        float2 v = make_float2(0.f, 0.f);
        if (node < N_NODES)
            v = *(const float2*)(data + (size_t)node * D + lane * 2);
        *(ushort2*)&Aw[m * 136 + lane * 2] = make_ushort2(f2bf(v.x), f2bf(v.y));
    }
    bf16x8 a[4];
#pragma unroll
    for (int kb = 0; kb < 4; ++kb)
        a[kb] = *(const bf16x8*)&Aw[m16 * 136 + kb * 32 + q * 8];
    f32x4 acc[8];
#pragma unroll
    for (int t = 0; t < 8; ++t) {
        acc[t] = (f32x4){0.f, 0.f, 0.f, 0.f};
#pragma unroll
        for (int kb = 0; kb < 4; ++kb) {
            bf16x8 bfr = *(const bf16x8*)&Wl[(((kb * 4 + q) * 128) + t * 16 + m16) * 8];
            acc[t] = __builtin_amdgcn_mfma_f32_16x16x32_bf16(a[kb], bfr, acc[t], 0, 0, 0);
        }
    }
    __syncthreads();
    float* Ew = (float*)(lds + wv * 8448);
#pragma unroll
    for (int t = 0; t < 8; ++t)
#pragma unroll
        for (int r = 0; r < 4; ++r)
            Ew[(q * 4 + r) * 132 + t * 16 + m16] = acc[t][r];
    const int h  = lane >> 5;
    const int c4 = (lane & 31) << 2;
#pragma unroll
    for (int j = 0; j < 8; ++j) {
        int r = j * 2 + h;
        int node = nb + r;
        if (node < N_NODES) {
            float4 v  = *(const float4*)&Ew[r * 132 + c4];
            float4 xi = *(const float4*)(x + (size_t)node * D + c4);
            float4 o;
            o.x = fmaxf(v.x, 0.f) + xi.x;
            o.y = fmaxf(v.y, 0.f) + xi.y;
            o.z = fmaxf(v.z, 0.f) + xi.z;
            o.w = fmaxf(v.w, 0.f) + xi.w;
            *(float4*)(data + (size_t)node * D + c4) = o;
        }
    }
}

extern "C" void kernel_launch(void* const* d_in, const int* in_sizes, int n_in,
                              void* d_out, int out_size, void* d_ws, size_t ws_size,
                              hipStream_t stream) {
    const float* x   = (const float*)d_in[0];
    const int*   src = (const int*)d_in[1];   // harness passes integers as int32
    const int*   dst = (const int*)d_in[2];
    const float* W   = (const float*)d_in[3];
    float* out = (float*)d_out;

    char* ws = (char*)d_ws;
    int*      bcnt  = (int*)ws;      ws += (size_t)SBP * 64;               // 200 KB
    unsigned* pairs = (unsigned*)ws; ws += (size_t)SB * WCAP16 * 4;        // 4.8 MB
    ushort*   snode = (ushort*)ws;   ws += (size_t)SB * WCAP16 * 2;        // 2.4 MB
    int*      od    = (int*)ws;      ws += (size_t)SB * 16 * 4;            // 200 KB
    ushort*   xb    = (ushort*)ws;   ws += (size_t)N_NODES * D * 2;        // 12.8 MB
    ushort*   aggS  = (ushort*)ws;   ws += (size_t)4 * SHARD_STRIDE * 2;   // 12.8 MB
    const bool big_ws = (ws_size >= (size_t)(ws - (char*)d_ws));

    if (big_ws) {
        convert_x<<<CONV_BLOCKS, 256, 0, stream>>>((const float4*)x, xb, bcnt);
        scatter_radix<<<SBLK, 1024, 0, stream>>>(src, dst, bcnt, pairs);
        node_sort<<<SB, 256, 0, stream>>>(pairs, bcnt, snode, od);
        gather_shard<<<SB * 4, 256, 0, stream>>>(snode, od, xb, aggS);
        gemm_relu_res<<<(N_NODES + 63) / 64, 256, 0, stream>>>(aggS, W, xb, out);
    } else {
        // slow-but-correct fallback (no scratch needed beyond d_out)
        int n4 = N_NODES * D / 4;
        zero_out<<<(n4 + 255) / 256, 256, 0, stream>>>((float4*)out, n4);
        long long n_scatter = (long long)N_EDGES * 32;
        scatter_edges<<<(int)((n_scatter + 255) / 256), 256, 0, stream>>>(
            x, src, dst, out);
        gemm_relu_res_f32<<<(N_NODES + 63) / 64, 256, 0, stream>>>(out, W, x);
    }
}